// Round 8
// baseline (125.719 us; speedup 1.0000x reference)
//
#include <hip/hip_runtime.h>
#include <math.h>

#define N_NODES 50000
#define N_EDGES 800000
#define IN_DIM 256
#define OUT_DIM 128
#define ALPHA 0.2f

#define GEMM_NB 782          // ceil(50000 / 64) ; 4 waves/block, 16 rows/wave
#define DEG_NB  3125         // (N_EDGES+255)/256
#define SCAN_NB 196          // (N_NODES+255)/256

typedef __attribute__((ext_vector_type(8))) short short8;
typedef __attribute__((ext_vector_type(4))) float f32x4;

// ---------------- workspace layout (bytes) ----------------
#define OFF_ZB     0u            // z bf16: 12,800,000
#define OFF_S1     12800000u
#define OFF_S2     13000000u
#define OFF_DEG    13200000u
#define OFF_OFFS   13400000u
#define OFF_OFFS2  13600000u     // 50001 ints (folded offsets + sentinel)
#define OFF_BSUM   13800064u
#define OFF_RANK   13801088u     // u16: 1,600,000
#define OFF_SRCS   15401088u     // u16: 1,600,000
#define OFF_WT     17001088u
#define OFF_WA1    17066624u
#define OFF_WA2    17067648u
// total ~17.1 MB

static __device__ __forceinline__ unsigned short f2bf_rne(float f) {
    unsigned int u = __float_as_uint(f);
    unsigned int r = (u + 0x7FFFu + ((u >> 16) & 1u)) >> 16;
    return (unsigned short)r;
}
static __device__ __forceinline__ unsigned int pack2bf(float lo, float hi) {
    return (unsigned int)f2bf_rne(lo) | ((unsigned int)f2bf_rne(hi) << 16);
}

// ---------------- prep: wa1/wa2 = W·a1 / W·a2 (f32), WT = bf16(W)^T ----------------
__global__ __launch_bounds__(256) void prep(const float* __restrict__ W,
                                            const float* __restrict__ attn,
                                            float* __restrict__ wa1,
                                            float* __restrict__ wa2,
                                            unsigned short* __restrict__ WT) {
    int b = blockIdx.x, t = threadIdx.x;
    if (b < 4) {
        int k = b * 64 + (t >> 2), kq = t & 3;
        float p1 = 0.f, p2 = 0.f;
#pragma unroll
        for (int j = 0; j < 8; j++) {
            int c = kq * 32 + j * 4;
            const float4 w  = *(const float4*)(W + (size_t)k * OUT_DIM + c);
            const float4 a1 = *(const float4*)(attn + c);
            const float4 a2 = *(const float4*)(attn + OUT_DIM + c);
            p1 += w.x * a1.x + w.y * a1.y + w.z * a1.z + w.w * a1.w;
            p2 += w.x * a2.x + w.y * a2.y + w.z * a2.z + w.w * a2.w;
        }
        p1 += __shfl_xor(p1, 1); p1 += __shfl_xor(p1, 2);
        p2 += __shfl_xor(p2, 1); p2 += __shfl_xor(p2, 2);
        if (kq == 0) { wa1[k] = p1; wa2[k] = p2; }
    } else {
        int idx = ((b - 4) * 256 + t) * 8;
        int c = idx >> 8, k0 = idx & 255;
        unsigned int uu[4];
#pragma unroll
        for (int q = 0; q < 4; q++) {
            float lo = W[(size_t)(k0 + 2 * q) * OUT_DIM + c];
            float hi = W[(size_t)(k0 + 2 * q + 1) * OUT_DIM + c];
            uu[q] = pack2bf(lo, hi);
        }
        *(uint4*)(WT + idx) = make_uint4(uu[0], uu[1], uu[2], uu[3]);
    }
}

// ---------------- fused: LDS-free MFMA GEMM (+s1/s2)  ||  deg_rank ----------------
// GEMM: no __shared__, no barriers. Each wave owns 16 rows x 128 cols.
// A-frag loaded straight from h (f32 -> bf16 in reg); B-frag straight from
// L2-hot WT (64 KB). 8 independent K-iters -> compiler pipelines, TLP hides L2.
__global__ __launch_bounds__(256) void gemm_deg(const float* __restrict__ h,
                                                const unsigned short* __restrict__ WT,
                                                const float* __restrict__ wa1,
                                                const float* __restrict__ wa2,
                                                unsigned short* __restrict__ zb,
                                                float* __restrict__ s1,
                                                float* __restrict__ s2,
                                                const int* __restrict__ dst,
                                                int* __restrict__ deg,
                                                unsigned short* __restrict__ rank) {
    const int t = threadIdx.x;

    if (blockIdx.x >= GEMM_NB) {           // ---- deg_rank path ----
        int e = (blockIdx.x - GEMM_NB) * 256 + t;
        if (e < N_EDGES) rank[e] = (unsigned short)atomicAdd(&deg[dst[e]], 1);
        return;
    }

    // ---- GEMM path ----
    const int lane = t & 63, w = t >> 6;
    const int m16 = lane & 15, kb = lane >> 4;     // A row-in-tile / k-group
    const int r0 = (blockIdx.x * 4 + w) * 16;      // wave's 16-row tile
    const int r  = r0 + m16;
    const float* hrow = h + (size_t)min(r, N_NODES - 1) * IN_DIM;

    f32x4 acc[8];
#pragma unroll
    for (int ct = 0; ct < 8; ct++) acc[ct] = (f32x4){0.f, 0.f, 0.f, 0.f};
    float p1 = 0.f, p2 = 0.f;

#pragma unroll
    for (int i = 0; i < 8; i++) {
        const int k = i * 32 + kb * 8;             // this lane's 8-elem k-slice
        const float4 v0 = *(const float4*)(hrow + k);
        const float4 v1 = *(const float4*)(hrow + k + 4);
        const float4 a0 = *(const float4*)(wa1 + k);
        const float4 a1 = *(const float4*)(wa1 + k + 4);
        const float4 b0 = *(const float4*)(wa2 + k);
        const float4 b1 = *(const float4*)(wa2 + k + 4);
        p1 += v0.x * a0.x + v0.y * a0.y + v0.z * a0.z + v0.w * a0.w
            + v1.x * a1.x + v1.y * a1.y + v1.z * a1.z + v1.w * a1.w;
        p2 += v0.x * b0.x + v0.y * b0.y + v0.z * b0.z + v0.w * b0.w
            + v1.x * b1.x + v1.y * b1.y + v1.z * b1.z + v1.w * b1.w;
        short8 af;
        af[0] = (short)f2bf_rne(v0.x); af[1] = (short)f2bf_rne(v0.y);
        af[2] = (short)f2bf_rne(v0.z); af[3] = (short)f2bf_rne(v0.w);
        af[4] = (short)f2bf_rne(v1.x); af[5] = (short)f2bf_rne(v1.y);
        af[6] = (short)f2bf_rne(v1.z); af[7] = (short)f2bf_rne(v1.w);
#pragma unroll
        for (int ct = 0; ct < 8; ct++) {
            const short8 bf = *(const short8*)(WT + (size_t)(ct * 16 + m16) * IN_DIM + k);
            acc[ct] = __builtin_amdgcn_mfma_f32_16x16x32_bf16(af, bf, acc[ct], 0, 0, 0);
        }
    }

    // s1/s2: sum the 4 kb-groups holding row r's k-slices
    p1 += __shfl_xor(p1, 16); p1 += __shfl_xor(p1, 32);
    p2 += __shfl_xor(p2, 16); p2 += __shfl_xor(p2, 32);
    if (lane < 16 && r < N_NODES) { s1[r] = p1; s2[r] = p2; }

    // C/D: col = ct*16 + m16, row = r0 + kb*4 + i
#pragma unroll
    for (int ct = 0; ct < 8; ct++) {
        int col = ct * 16 + m16;
#pragma unroll
        for (int i = 0; i < 4; i++) {
            int rr = r0 + kb * 4 + i;
            if (rr < N_NODES) zb[(size_t)rr * OUT_DIM + col] = f2bf_rne(acc[ct][i]);
        }
    }
}

// ---------------- per-256-chunk exclusive scan of deg ----------------
__global__ __launch_bounds__(256) void scan1(const int* __restrict__ deg, int* __restrict__ offs,
                                             int* __restrict__ blocksum) {
    __shared__ int s[256];
    int t = threadIdx.x;
    int i = blockIdx.x * 256 + t;
    int d = (i < N_NODES) ? deg[i] : 0;
    s[t] = d;
    __syncthreads();
    int v = d;
    for (int ofs = 1; ofs < 256; ofs <<= 1) {
        int add = (t >= ofs) ? s[t - ofs] : 0;
        __syncthreads();
        v += add;
        s[t] = v;
        __syncthreads();
    }
    if (i < N_NODES) offs[i] = v - d;
    if (t == 255) blocksum[blockIdx.x] = v;
}

// ---------------- scatter (in-LDS scan of blocksums; emits folded offs2) ----------------
__global__ __launch_bounds__(256) void scatter_k(const int* __restrict__ src, const int* __restrict__ dst,
                                                 const unsigned short* __restrict__ rank,
                                                 const int* __restrict__ offs,
                                                 const int* __restrict__ blocksum,
                                                 unsigned short* __restrict__ srcs,
                                                 int* __restrict__ offs2) {
    __shared__ int sbo[256];
    int t = threadIdx.x;
    int d0 = (t < SCAN_NB) ? blocksum[t] : 0;
    sbo[t] = d0;
    __syncthreads();
    int v = d0;
    for (int ofs = 1; ofs < 256; ofs <<= 1) {
        int add = (t >= ofs) ? sbo[t - ofs] : 0;
        __syncthreads();
        v += add;
        sbo[t] = v;
        __syncthreads();
    }
    int excl = (t > 0) ? sbo[t - 1] : 0;
    __syncthreads();
    sbo[t] = excl;
    __syncthreads();

    if (blockIdx.x < SCAN_NB) {
        int i = blockIdx.x * 256 + t;
        if (i < N_NODES) offs2[i] = offs[i] + sbo[blockIdx.x];
        if (blockIdx.x == 0 && t == 0) offs2[N_NODES] = N_EDGES;
    }

    int e = blockIdx.x * 256 + t;
    if (e < N_EDGES) {
        int d = dst[e];
        int pos = offs[d] + sbo[d >> 8] + (int)rank[e];
        srcs[pos] = (unsigned short)src[e];
    }
}

// ---------------- per-dst softmax + weighted gather-sum (single pass, no max) ----------------
// R6 lesson: gather-bound; scalar phase fully hidden. Left untouched as control.
__global__ __launch_bounds__(256) void aggregate(const unsigned short* __restrict__ zb,
                                                 const int* __restrict__ offs2,
                                                 const unsigned short* __restrict__ srcs,
                                                 const float* __restrict__ s1,
                                                 const float* __restrict__ s2,
                                                 float* __restrict__ out) {
    int wid = (blockIdx.x * blockDim.x + threadIdx.x) >> 6;
    int lane = threadIdx.x & 63;
    if (wid >= N_NODES) return;
    const int g = lane >> 3;
    const int l = lane & 7;
    float* outp = out + (size_t)wid * OUT_DIM + l * 16 + g * 2;

    int base = offs2[wid];
    int len = offs2[wid + 1] - base;
    if (len == 0) {
        *(float2*)outp = make_float2(0.f, 0.f);
        return;
    }
    const float s2v = s2[wid];

    float sum = 0.f;
    float acc[16];
#pragma unroll
    for (int k = 0; k < 16; k++) acc[k] = 0.f;

    for (int c0 = 0; c0 < len; c0 += 64) {
        int i = c0 + lane;
        float ex = 0.f;
        int sj = 0;
        if (i < len) {
            sj = srcs[base + i];
            float lg = s1[sj] + s2v;
            lg = (lg >= 0.f) ? lg : ALPHA * lg;
            ex = __expf(lg);
        }
        sum += ex;
        int cnt = min(64, len - c0);
        for (int j0 = 0; j0 < cnt; j0 += 8) {
            int j = j0 + g;
            float wj = __shfl(ex, j);
            int s = __shfl(sj, j);
            if (j < cnt) {
                const uint4* rp = (const uint4*)(zb + (size_t)s * OUT_DIM);
                const uint4 v0 = rp[l * 2];
                const uint4 v1 = rp[l * 2 + 1];
#pragma unroll
                for (int k = 0; k < 4; k++) {
                    unsigned int w = (&v0.x)[k];
                    acc[2 * k]     += wj * __uint_as_float(w << 16);
                    acc[2 * k + 1] += wj * __uint_as_float(w & 0xFFFF0000u);
                }
#pragma unroll
                for (int k = 0; k < 4; k++) {
                    unsigned int w = (&v1.x)[k];
                    acc[8 + 2 * k]     += wj * __uint_as_float(w << 16);
                    acc[8 + 2 * k + 1] += wj * __uint_as_float(w & 0xFFFF0000u);
                }
            }
        }
    }
#pragma unroll
    for (int k = 0; k < 16; k++) {
        acc[k] += __shfl_xor(acc[k], 8);
        acc[k] += __shfl_xor(acc[k], 16);
        acc[k] += __shfl_xor(acc[k], 32);
    }
#pragma unroll
    for (int m = 32; m >= 1; m >>= 1) sum += __shfl_xor(sum, m);
    float inv = (sum > 0.f) ? 1.f / sum : 1.f;

    float a0 = acc[g * 2] * inv;
    float a1 = acc[g * 2 + 1] * inv;
    float2 o;
    o.x = (a0 > 0.f) ? a0 : expm1f(a0);
    o.y = (a1 > 0.f) ? a1 : expm1f(a1);
    *(float2*)outp = o;
}

// ---------------- launcher ----------------
extern "C" void kernel_launch(void* const* d_in, const int* in_sizes, int n_in,
                              void* d_out, int out_size, void* d_ws, size_t ws_size,
                              hipStream_t stream) {
    const float* h      = (const float*)d_in[0];
    const int*   src    = (const int*)d_in[1];
    const int*   dst    = (const int*)d_in[2];
    const float* W_fc   = (const float*)d_in[3];
    const float* attn_w = (const float*)d_in[4];
    float* out = (float*)d_out;

    char* ws = (char*)d_ws;
    unsigned short* zb = (unsigned short*)(ws + OFF_ZB);
    float* s1       = (float*)(ws + OFF_S1);
    float* s2       = (float*)(ws + OFF_S2);
    int*   deg      = (int*)(ws + OFF_DEG);
    int*   offs     = (int*)(ws + OFF_OFFS);
    int*   offs2    = (int*)(ws + OFF_OFFS2);
    int*   blocksum = (int*)(ws + OFF_BSUM);
    unsigned short* rank = (unsigned short*)(ws + OFF_RANK);
    unsigned short* srcs = (unsigned short*)(ws + OFF_SRCS);
    unsigned short* WT = (unsigned short*)(ws + OFF_WT);
    float* wa1      = (float*)(ws + OFF_WA1);
    float* wa2      = (float*)(ws + OFF_WA2);

    hipMemsetAsync(deg, 0, N_NODES * sizeof(int), stream);

    prep<<<20, 256, 0, stream>>>(W_fc, attn_w, wa1, wa2, WT);
    gemm_deg<<<GEMM_NB + DEG_NB, 256, 0, stream>>>(h, WT, wa1, wa2, zb, s1, s2,
                                                   dst, deg, rank);
    scan1<<<SCAN_NB, 256, 0, stream>>>(deg, offs, blocksum);
    scatter_k<<<DEG_NB, 256, 0, stream>>>(src, dst, rank, offs, blocksum, srcs, offs2);
    aggregate<<<(N_NODES * 64) / 256, 256, 0, stream>>>(zb, offs2, srcs, s1, s2, out);
}

// Round 9
// 116.538 us; speedup vs baseline: 1.0788x; 1.0788x over previous
//
#include <hip/hip_runtime.h>
#include <math.h>

#define N_NODES 50000
#define N_EDGES 800000
#define IN_DIM 256
#define OUT_DIM 128
#define ALPHA 0.2f

#define WT_NB   16
#define CVT_NB  3125
#define DEG_NB  3125
#define GEMM_NB 391          // ceil(50000/128), 8 waves, 16 rows/wave
#define SCAN_NB 196

typedef __attribute__((ext_vector_type(8))) short short8;
typedef __attribute__((ext_vector_type(4))) float f32x4;

// ---------------- workspace layout (bytes) ----------------
#define OFF_ZB    0u          // z bf16: 12,800,000
#define OFF_HB    12800000u   // h bf16: 25,600,000
#define OFF_S1    38400000u
#define OFF_S2    38600000u
#define OFF_DEG   38800000u
#define OFF_OFFS  39000000u
#define OFF_OFFS2 39200000u   // 50001 ints
#define OFF_BSUM  39400064u
#define OFF_RANK  39401088u   // u16
#define OFF_SRCS  41001088u   // u16
#define OFF_WT    42601088u   // 65,536
// total ~42.7 MB

static __device__ __forceinline__ unsigned short f2bf_rne(float f) {
    unsigned int u = __float_as_uint(f);
    unsigned int r = (u + 0x7FFFu + ((u >> 16) & 1u)) >> 16;
    return (unsigned short)r;
}
static __device__ __forceinline__ unsigned int pack2bf(float lo, float hi) {
    return (unsigned int)f2bf_rne(lo) | ((unsigned int)f2bf_rne(hi) << 16);
}

// ---------------- fused early pass: WT transpose | h->bf16 | deg+rank ----------------
__global__ __launch_bounds__(256) void prep_cvt_deg(const float* __restrict__ h,
                                                    const float* __restrict__ W,
                                                    unsigned short* __restrict__ WT,
                                                    unsigned short* __restrict__ hb,
                                                    const int* __restrict__ dst,
                                                    int* __restrict__ deg,
                                                    unsigned short* __restrict__ rank) {
    int b = blockIdx.x, t = threadIdx.x;
    if (b < WT_NB) {
        // WT[c][k] = bf16(W[k][c])
        int idx = (b * 256 + t) * 8;
        int c = idx >> 8, k0 = idx & 255;
        unsigned int uu[4];
#pragma unroll
        for (int q = 0; q < 4; q++) {
            float lo = W[(size_t)(k0 + 2 * q) * OUT_DIM + c];
            float hi = W[(size_t)(k0 + 2 * q + 1) * OUT_DIM + c];
            uu[q] = pack2bf(lo, hi);
        }
        *(uint4*)(WT + idx) = make_uint4(uu[0], uu[1], uu[2], uu[3]);
    } else if (b < WT_NB + CVT_NB) {
        // h (f32) -> hb (bf16), wave per row, 4 rows per wave
        int wv = (b - WT_NB) * 4 + (t >> 6);
        int lane = t & 63;
        for (int r = wv; r < N_NODES; r += 12500) {
            const float4 v = *(const float4*)(h + (size_t)r * IN_DIM + lane * 4);
            ushort4 o;
            o.x = f2bf_rne(v.x); o.y = f2bf_rne(v.y);
            o.z = f2bf_rne(v.z); o.w = f2bf_rne(v.w);
            *(ushort4*)(hb + (size_t)r * IN_DIM + lane * 4) = o;
        }
    } else {
        int e = (b - WT_NB - CVT_NB) * 256 + t;
        if (e < N_EDGES) rank[e] = (unsigned short)atomicAdd(&deg[dst[e]], 1);
    }
}

// ---------------- GEMM (B resident in LDS, barrier-free K-loop) | scan1 ----------------
// 512 threads = 8 waves. Tile 128 rows x 128 cols, K=256.
// B: 128 cols x 256 k bf16 = 64KB LDS, XOR-swizzled slot = G ^ (col&7) (G = 16B granule).
// A: straight from hb, one uint4 per (wave-lane, kc), prefetched 1 kc ahead.
// Epilogue: s1/s2 = z . a1/a2 from the f32 accumulators (exact-accum bf16-input z).
__global__ __launch_bounds__(512) void gemm_scan(const unsigned short* __restrict__ hb,
                                                 const unsigned short* __restrict__ WT,
                                                 const float* __restrict__ attn,
                                                 unsigned short* __restrict__ zb,
                                                 float* __restrict__ s1,
                                                 float* __restrict__ s2,
                                                 const int* __restrict__ deg,
                                                 int* __restrict__ offs,
                                                 int* __restrict__ blocksum) {
    __shared__ char smem[65536];
    const int t = threadIdx.x;

    if (blockIdx.x >= GEMM_NB) {
        // ---- scan1 path (256 active threads, barrier-uniform for 512) ----
        int* s = (int*)smem;
        int bi = blockIdx.x - GEMM_NB;
        int i = bi * 256 + t;
        int d = 0;
        if (t < 256) { d = (i < N_NODES) ? deg[i] : 0; s[t] = d; }
        __syncthreads();
        int v = d;
        for (int ofs = 1; ofs < 256; ofs <<= 1) {
            int add = (t < 256 && t >= ofs) ? s[t - ofs] : 0;
            __syncthreads();
            if (t < 256) { v += add; s[t] = v; }
            __syncthreads();
        }
        if (t < 256) {
            if (i < N_NODES) offs[i] = v - d;
            if (t == 255) blocksum[bi] = v;
        }
        return;
    }

    // ---- GEMM path ----
    const int lane = t & 63, w = t >> 6;
    const int row0 = blockIdx.x * 128;
    const int m16 = lane & 15, kb = lane >> 4;

    // stage B once: linear global read, swizzled LDS write
#pragma unroll
    for (int j = 0; j < 8; j++) {
        int jj = w * 8 + j;                 // 0..63, 2 cols each
        int cc = jj * 2 + (lane >> 5);      // col 0..127
        int gs = lane & 31;                 // logical 16B granule 0..31
        const uint4 v = *(const uint4*)(WT + (size_t)cc * IN_DIM + gs * 8);
        *(uint4*)(smem + cc * 512 + ((gs ^ (cc & 7)) * 16)) = v;
    }
    __syncthreads();

    const int rA = row0 + w * 16 + m16;
    const unsigned short* ap = hb + (size_t)min(rA, N_NODES - 1) * IN_DIM + kb * 8;

    f32x4 acc[8];
#pragma unroll
    for (int ct = 0; ct < 8; ct++) acc[ct] = (f32x4){0.f, 0.f, 0.f, 0.f};

    union U { uint4 u; short8 s; };
    uint4 a_next = *(const uint4*)ap;       // kc = 0
#pragma unroll
    for (int kc = 0; kc < 8; kc++) {
        U ua; ua.u = a_next;
        if (kc < 7) a_next = *(const uint4*)(ap + (kc + 1) * 32);
        const short8 af = ua.s;
        const char* bbase = smem + m16 * 512 + (((kc * 4 + kb) ^ (m16 & 7)) * 16);
#pragma unroll
        for (int ct = 0; ct < 8; ct++) {
            const short8 bf = *(const short8*)(bbase + ct * 8192);
            acc[ct] = __builtin_amdgcn_mfma_f32_16x16x32_bf16(af, bf, acc[ct], 0, 0, 0);
        }
    }

    // ---- epilogue: s1/s2 from f32 acc, zb bf16 store ----
    float a1v[8], a2v[8];
#pragma unroll
    for (int ct = 0; ct < 8; ct++) {
        a1v[ct] = attn[ct * 16 + m16];
        a2v[ct] = attn[OUT_DIM + ct * 16 + m16];
    }
#pragma unroll
    for (int i = 0; i < 4; i++) {
        int rr = row0 + w * 16 + kb * 4 + i;    // C/D: row = kb*4 + reg, col = ct*16+m16
        float q1 = 0.f, q2 = 0.f;
#pragma unroll
        for (int ct = 0; ct < 8; ct++) {
            q1 += acc[ct][i] * a1v[ct];
            q2 += acc[ct][i] * a2v[ct];
        }
        q1 += __shfl_xor(q1, 1); q1 += __shfl_xor(q1, 2);
        q1 += __shfl_xor(q1, 4); q1 += __shfl_xor(q1, 8);
        q2 += __shfl_xor(q2, 1); q2 += __shfl_xor(q2, 2);
        q2 += __shfl_xor(q2, 4); q2 += __shfl_xor(q2, 8);
        if (m16 == 0 && rr < N_NODES) { s1[rr] = q1; s2[rr] = q2; }
        if (rr < N_NODES) {
#pragma unroll
            for (int ct = 0; ct < 8; ct++)
                zb[(size_t)rr * OUT_DIM + ct * 16 + m16] = f2bf_rne(acc[ct][i]);
        }
    }
}

// ---------------- scatter (in-LDS scan of blocksums; emits folded offs2) ----------------
__global__ __launch_bounds__(256) void scatter_k(const int* __restrict__ src, const int* __restrict__ dst,
                                                 const unsigned short* __restrict__ rank,
                                                 const int* __restrict__ offs,
                                                 const int* __restrict__ blocksum,
                                                 unsigned short* __restrict__ srcs,
                                                 int* __restrict__ offs2) {
    __shared__ int sbo[256];
    int t = threadIdx.x;
    int d0 = (t < SCAN_NB) ? blocksum[t] : 0;
    sbo[t] = d0;
    __syncthreads();
    int v = d0;
    for (int ofs = 1; ofs < 256; ofs <<= 1) {
        int add = (t >= ofs) ? sbo[t - ofs] : 0;
        __syncthreads();
        v += add;
        sbo[t] = v;
        __syncthreads();
    }
    int excl = (t > 0) ? sbo[t - 1] : 0;
    __syncthreads();
    sbo[t] = excl;
    __syncthreads();

    if (blockIdx.x < SCAN_NB) {
        int i = blockIdx.x * 256 + t;
        if (i < N_NODES) offs2[i] = offs[i] + sbo[blockIdx.x];
        if (blockIdx.x == 0 && t == 0) offs2[N_NODES] = N_EDGES;
    }

    int e = blockIdx.x * 256 + t;
    if (e < N_EDGES) {
        int d = dst[e];
        int pos = offs[d] + sbo[d >> 8] + (int)rank[e];
        srcs[pos] = (unsigned short)src[e];
    }
}

// ---------------- per-dst softmax + weighted gather-sum (unchanged control) ----------------
__global__ __launch_bounds__(256) void aggregate(const unsigned short* __restrict__ zb,
                                                 const int* __restrict__ offs2,
                                                 const unsigned short* __restrict__ srcs,
                                                 const float* __restrict__ s1,
                                                 const float* __restrict__ s2,
                                                 float* __restrict__ out) {
    int wid = (blockIdx.x * blockDim.x + threadIdx.x) >> 6;
    int lane = threadIdx.x & 63;
    if (wid >= N_NODES) return;
    const int g = lane >> 3;
    const int l = lane & 7;
    float* outp = out + (size_t)wid * OUT_DIM + l * 16 + g * 2;

    int base = offs2[wid];
    int len = offs2[wid + 1] - base;
    if (len == 0) {
        *(float2*)outp = make_float2(0.f, 0.f);
        return;
    }
    const float s2v = s2[wid];

    float sum = 0.f;
    float acc[16];
#pragma unroll
    for (int k = 0; k < 16; k++) acc[k] = 0.f;

    for (int c0 = 0; c0 < len; c0 += 64) {
        int i = c0 + lane;
        float ex = 0.f;
        int sj = 0;
        if (i < len) {
            sj = srcs[base + i];
            float lg = s1[sj] + s2v;
            lg = (lg >= 0.f) ? lg : ALPHA * lg;
            ex = __expf(lg);
        }
        sum += ex;
        int cnt = min(64, len - c0);
        for (int j0 = 0; j0 < cnt; j0 += 8) {
            int j = j0 + g;
            float wj = __shfl(ex, j);
            int s = __shfl(sj, j);
            if (j < cnt) {
                const uint4* rp = (const uint4*)(zb + (size_t)s * OUT_DIM);
                const uint4 v0 = rp[l * 2];
                const uint4 v1 = rp[l * 2 + 1];
#pragma unroll
                for (int k = 0; k < 4; k++) {
                    unsigned int w = (&v0.x)[k];
                    acc[2 * k]     += wj * __uint_as_float(w << 16);
                    acc[2 * k + 1] += wj * __uint_as_float(w & 0xFFFF0000u);
                }
#pragma unroll
                for (int k = 0; k < 4; k++) {
                    unsigned int w = (&v1.x)[k];
                    acc[8 + 2 * k]     += wj * __uint_as_float(w << 16);
                    acc[8 + 2 * k + 1] += wj * __uint_as_float(w & 0xFFFF0000u);
                }
            }
        }
    }
#pragma unroll
    for (int k = 0; k < 16; k++) {
        acc[k] += __shfl_xor(acc[k], 8);
        acc[k] += __shfl_xor(acc[k], 16);
        acc[k] += __shfl_xor(acc[k], 32);
    }
#pragma unroll
    for (int m = 32; m >= 1; m >>= 1) sum += __shfl_xor(sum, m);
    float inv = (sum > 0.f) ? 1.f / sum : 1.f;

    float a0 = acc[g * 2] * inv;
    float a1 = acc[g * 2 + 1] * inv;
    float2 o;
    o.x = (a0 > 0.f) ? a0 : expm1f(a0);
    o.y = (a1 > 0.f) ? a1 : expm1f(a1);
    *(float2*)outp = o;
}

// ---------------- launcher ----------------
extern "C" void kernel_launch(void* const* d_in, const int* in_sizes, int n_in,
                              void* d_out, int out_size, void* d_ws, size_t ws_size,
                              hipStream_t stream) {
    const float* h      = (const float*)d_in[0];
    const int*   src    = (const int*)d_in[1];
    const int*   dst    = (const int*)d_in[2];
    const float* W_fc   = (const float*)d_in[3];
    const float* attn_w = (const float*)d_in[4];
    float* out = (float*)d_out;

    char* ws = (char*)d_ws;
    unsigned short* zb = (unsigned short*)(ws + OFF_ZB);
    unsigned short* hb = (unsigned short*)(ws + OFF_HB);
    float* s1       = (float*)(ws + OFF_S1);
    float* s2       = (float*)(ws + OFF_S2);
    int*   deg      = (int*)(ws + OFF_DEG);
    int*   offs     = (int*)(ws + OFF_OFFS);
    int*   offs2    = (int*)(ws + OFF_OFFS2);
    int*   blocksum = (int*)(ws + OFF_BSUM);
    unsigned short* rank = (unsigned short*)(ws + OFF_RANK);
    unsigned short* srcs = (unsigned short*)(ws + OFF_SRCS);
    unsigned short* WT = (unsigned short*)(ws + OFF_WT);

    hipMemsetAsync(deg, 0, N_NODES * sizeof(int), stream);

    prep_cvt_deg<<<WT_NB + CVT_NB + DEG_NB, 256, 0, stream>>>(h, W_fc, WT, hb, dst, deg, rank);
    gemm_scan<<<GEMM_NB + SCAN_NB, 512, 0, stream>>>(hb, WT, attn_w, zb, s1, s2,
                                                     deg, offs, blocksum);
    scatter_k<<<DEG_NB, 256, 0, stream>>>(src, dst, rank, offs, blocksum, srcs, offs2);
    aggregate<<<(N_NODES * 64) / 256, 256, 0, stream>>>(zb, offs2, srcs, s1, s2, out);
}

// Round 10
// 111.558 us; speedup vs baseline: 1.1269x; 1.0446x over previous
//
#include <hip/hip_runtime.h>
#include <math.h>

#define N_NODES 50000
#define N_EDGES 800000
#define IN_DIM 256
#define OUT_DIM 128
#define ALPHA 0.2f

#define DEG_NB  3125         // (N_EDGES+255)/256
#define WT_NB   16
#define GEMM_NB 391          // ceil(50000/128), 8 waves, 16 rows/wave
#define SCAN_NB 196          // (N_NODES+255)/256

typedef __attribute__((ext_vector_type(8))) short short8;
typedef __attribute__((ext_vector_type(4))) float f32x4;

// ---------------- workspace layout (bytes) ----------------
#define OFF_ZB    0u          // z bf16: 12,800,000
#define OFF_S1    12800000u
#define OFF_S2    13000000u
#define OFF_DEG8  13200000u   // 8 * 50000 * 4 = 1,600,000 (XCD-partitioned counters)
#define OFF_OFFS  14800000u
#define OFF_OFFS2 15000000u   // 50001 ints
#define OFF_BSUM  15200064u
#define OFF_RANK  15201088u   // u16: 1,600,000
#define OFF_SRCS  16801088u   // u16: 1,600,000
#define OFF_WT    18401088u   // 65,536
#define OFF_PRE8  18466624u   // u16: 50000*8*2 = 800,000 (per-dst partition prefix)
// total ~19.3 MB

static __device__ __forceinline__ unsigned short f2bf_rne(float f) {
    unsigned int u = __float_as_uint(f);
    unsigned int r = (u + 0x7FFFu + ((u >> 16) & 1u)) >> 16;
    return (unsigned short)r;
}
static __device__ __forceinline__ unsigned int pack2bf(float lo, float hi) {
    return (unsigned int)f2bf_rne(lo) | ((unsigned int)f2bf_rne(hi) << 16);
}

// ---------------- deg+rank (XCD-partitioned atomics) | WT transpose ----------------
// blocks [0, DEG_NB): each block atomics into partition blockIdx&7 -> counter
// lines stay resident in ONE XCD's L2 (no cross-XCD ping-pong).
__global__ __launch_bounds__(256) void deg_wt(const float* __restrict__ W,
                                              const int* __restrict__ dst,
                                              int* __restrict__ deg8,
                                              unsigned short* __restrict__ rank,
                                              unsigned short* __restrict__ WT) {
    int b = blockIdx.x, t = threadIdx.x;
    if (b < DEG_NB) {
        int e = b * 256 + t;
        int x = b & 7;                       // pseudo-XCD partition
        if (e < N_EDGES)
            rank[e] = (unsigned short)atomicAdd(&deg8[x * N_NODES + dst[e]], 1);
    } else {
        int idx = ((b - DEG_NB) * 256 + t) * 8;   // WT[c][k] = bf16(W[k][c])
        int c = idx >> 8, k0 = idx & 255;
        unsigned int uu[4];
#pragma unroll
        for (int q = 0; q < 4; q++) {
            float lo = W[(size_t)(k0 + 2 * q) * OUT_DIM + c];
            float hi = W[(size_t)(k0 + 2 * q + 1) * OUT_DIM + c];
            uu[q] = pack2bf(lo, hi);
        }
        *(uint4*)(WT + idx) = make_uint4(uu[0], uu[1], uu[2], uu[3]);
    }
}

// ---------------- GEMM (B resident in LDS, barrier-free K-loop) | scan1+pre8 ----------------
// 512 threads = 8 waves. Tile 128 rows x 128 cols, K=256.
// A: straight from f32 h (32B/lane), converted to bf16 in-reg, prefetched 1 kc ahead.
// B: 64KB LDS, XOR-swizzled slot = G ^ (col&7). Epilogue: s1/s2 from f32 acc.
__global__ __launch_bounds__(512) void gemm_scan(const float* __restrict__ h,
                                                 const unsigned short* __restrict__ WT,
                                                 const float* __restrict__ attn,
                                                 unsigned short* __restrict__ zb,
                                                 float* __restrict__ s1,
                                                 float* __restrict__ s2,
                                                 const int* __restrict__ deg8,
                                                 int* __restrict__ offs,
                                                 int* __restrict__ blocksum,
                                                 unsigned short* __restrict__ pre8) {
    __shared__ char smem[65536];
    const int t = threadIdx.x;

    if (blockIdx.x >= GEMM_NB) {
        // ---- scan path: sum 8 partitions, emit pre8, chunk-scan totals ----
        int* s = (int*)smem;
        int bi = blockIdx.x - GEMM_NB;
        int i = bi * 256 + t;
        int tot = 0;
        if (t < 256 && i < N_NODES) {
            unsigned short pre[8];
#pragma unroll
            for (int x = 0; x < 8; x++) {
                pre[x] = (unsigned short)tot;
                tot += deg8[x * N_NODES + i];
            }
            ushort4 p0, p1;
            p0.x = pre[0]; p0.y = pre[1]; p0.z = pre[2]; p0.w = pre[3];
            p1.x = pre[4]; p1.y = pre[5]; p1.z = pre[6]; p1.w = pre[7];
            *(ushort4*)(pre8 + (size_t)i * 8) = p0;
            *(ushort4*)(pre8 + (size_t)i * 8 + 4) = p1;
        }
        if (t < 256) s[t] = tot;
        __syncthreads();
        int v = tot;
        for (int ofs = 1; ofs < 256; ofs <<= 1) {
            int add = (t < 256 && t >= ofs) ? s[t - ofs] : 0;
            __syncthreads();
            if (t < 256) { v += add; s[t] = v; }
            __syncthreads();
        }
        if (t < 256) {
            if (i < N_NODES) offs[i] = v - tot;
            if (t == 255) blocksum[bi] = v;
        }
        return;
    }

    // ---- GEMM path ----
    const int lane = t & 63, w = t >> 6;
    const int row0 = blockIdx.x * 128;
    const int m16 = lane & 15, kb = lane >> 4;

    // stage B once: linear global read, swizzled LDS write
#pragma unroll
    for (int j = 0; j < 8; j++) {
        int jj = w * 8 + j;
        int cc = jj * 2 + (lane >> 5);      // col 0..127
        int gs = lane & 31;                 // 16B granule 0..31
        const uint4 v = *(const uint4*)(WT + (size_t)cc * IN_DIM + gs * 8);
        *(uint4*)(smem + cc * 512 + ((gs ^ (cc & 7)) * 16)) = v;
    }
    __syncthreads();

    const int rA = row0 + w * 16 + m16;
    const float* hrow = h + (size_t)min(rA, N_NODES - 1) * IN_DIM + kb * 8;

    f32x4 acc[8];
#pragma unroll
    for (int ct = 0; ct < 8; ct++) acc[ct] = (f32x4){0.f, 0.f, 0.f, 0.f};

    float4 v0 = *(const float4*)(hrow);
    float4 v1 = *(const float4*)(hrow + 4);
#pragma unroll
    for (int kc = 0; kc < 8; kc++) {
        const float4 c0 = v0, c1 = v1;
        if (kc < 7) {
            v0 = *(const float4*)(hrow + (kc + 1) * 32);
            v1 = *(const float4*)(hrow + (kc + 1) * 32 + 4);
        }
        short8 af;
        af[0] = (short)f2bf_rne(c0.x); af[1] = (short)f2bf_rne(c0.y);
        af[2] = (short)f2bf_rne(c0.z); af[3] = (short)f2bf_rne(c0.w);
        af[4] = (short)f2bf_rne(c1.x); af[5] = (short)f2bf_rne(c1.y);
        af[6] = (short)f2bf_rne(c1.z); af[7] = (short)f2bf_rne(c1.w);
        const char* bbase = smem + m16 * 512 + (((kc * 4 + kb) ^ (m16 & 7)) * 16);
#pragma unroll
        for (int ct = 0; ct < 8; ct++) {
            const short8 bf = *(const short8*)(bbase + ct * 8192);
            acc[ct] = __builtin_amdgcn_mfma_f32_16x16x32_bf16(af, bf, acc[ct], 0, 0, 0);
        }
    }

    // ---- epilogue: s1/s2 from f32 acc, zb bf16 store ----
    float a1v[8], a2v[8];
#pragma unroll
    for (int ct = 0; ct < 8; ct++) {
        a1v[ct] = attn[ct * 16 + m16];
        a2v[ct] = attn[OUT_DIM + ct * 16 + m16];
    }
#pragma unroll
    for (int i = 0; i < 4; i++) {
        int rr = row0 + w * 16 + kb * 4 + i;    // C/D: row = kb*4 + reg, col = ct*16+m16
        float q1 = 0.f, q2 = 0.f;
#pragma unroll
        for (int ct = 0; ct < 8; ct++) {
            q1 += acc[ct][i] * a1v[ct];
            q2 += acc[ct][i] * a2v[ct];
        }
        q1 += __shfl_xor(q1, 1); q1 += __shfl_xor(q1, 2);
        q1 += __shfl_xor(q1, 4); q1 += __shfl_xor(q1, 8);
        q2 += __shfl_xor(q2, 1); q2 += __shfl_xor(q2, 2);
        q2 += __shfl_xor(q2, 4); q2 += __shfl_xor(q2, 8);
        if (m16 == 0 && rr < N_NODES) { s1[rr] = q1; s2[rr] = q2; }
        if (rr < N_NODES) {
#pragma unroll
            for (int ct = 0; ct < 8; ct++)
                zb[(size_t)rr * OUT_DIM + ct * 16 + m16] = f2bf_rne(acc[ct][i]);
        }
    }
}

// ---------------- scatter (in-LDS scan of blocksums; emits folded offs2) ----------------
__global__ __launch_bounds__(256) void scatter_k(const int* __restrict__ src, const int* __restrict__ dst,
                                                 const unsigned short* __restrict__ rank,
                                                 const int* __restrict__ offs,
                                                 const int* __restrict__ blocksum,
                                                 const unsigned short* __restrict__ pre8,
                                                 unsigned short* __restrict__ srcs,
                                                 int* __restrict__ offs2) {
    __shared__ int sbo[256];
    int t = threadIdx.x;
    int d0 = (t < SCAN_NB) ? blocksum[t] : 0;
    sbo[t] = d0;
    __syncthreads();
    int v = d0;
    for (int ofs = 1; ofs < 256; ofs <<= 1) {
        int add = (t >= ofs) ? sbo[t - ofs] : 0;
        __syncthreads();
        v += add;
        sbo[t] = v;
        __syncthreads();
    }
    int excl = (t > 0) ? sbo[t - 1] : 0;
    __syncthreads();
    sbo[t] = excl;
    __syncthreads();

    if (blockIdx.x < SCAN_NB) {
        int i = blockIdx.x * 256 + t;
        if (i < N_NODES) offs2[i] = offs[i] + sbo[blockIdx.x];
        if (blockIdx.x == 0 && t == 0) offs2[N_NODES] = N_EDGES;
    }

    int e = blockIdx.x * 256 + t;
    if (e < N_EDGES) {
        int d = dst[e];
        int x = (e >> 8) & 7;               // partition used in deg_wt (block e/256, &7)
        int pos = offs[d] + sbo[d >> 8] + (int)pre8[(size_t)d * 8 + x] + (int)rank[e];
        srcs[pos] = (unsigned short)src[e];
    }
}

// ---------------- per-dst softmax + weighted gather-sum (unchanged control) ----------------
__global__ __launch_bounds__(256) void aggregate(const unsigned short* __restrict__ zb,
                                                 const int* __restrict__ offs2,
                                                 const unsigned short* __restrict__ srcs,
                                                 const float* __restrict__ s1,
                                                 const float* __restrict__ s2,
                                                 float* __restrict__ out) {
    int wid = (blockIdx.x * blockDim.x + threadIdx.x) >> 6;
    int lane = threadIdx.x & 63;
    if (wid >= N_NODES) return;
    const int g = lane >> 3;
    const int l = lane & 7;
    float* outp = out + (size_t)wid * OUT_DIM + l * 16 + g * 2;

    int base = offs2[wid];
    int len = offs2[wid + 1] - base;
    if (len == 0) {
        *(float2*)outp = make_float2(0.f, 0.f);
        return;
    }
    const float s2v = s2[wid];

    float sum = 0.f;
    float acc[16];
#pragma unroll
    for (int k = 0; k < 16; k++) acc[k] = 0.f;

    for (int c0 = 0; c0 < len; c0 += 64) {
        int i = c0 + lane;
        float ex = 0.f;
        int sj = 0;
        if (i < len) {
            sj = srcs[base + i];
            float lg = s1[sj] + s2v;
            lg = (lg >= 0.f) ? lg : ALPHA * lg;
            ex = __expf(lg);
        }
        sum += ex;
        int cnt = min(64, len - c0);
        for (int j0 = 0; j0 < cnt; j0 += 8) {
            int j = j0 + g;
            float wj = __shfl(ex, j);
            int s = __shfl(sj, j);
            if (j < cnt) {
                const uint4* rp = (const uint4*)(zb + (size_t)s * OUT_DIM);
                const uint4 v0 = rp[l * 2];
                const uint4 v1 = rp[l * 2 + 1];
#pragma unroll
                for (int k = 0; k < 4; k++) {
                    unsigned int w = (&v0.x)[k];
                    acc[2 * k]     += wj * __uint_as_float(w << 16);
                    acc[2 * k + 1] += wj * __uint_as_float(w & 0xFFFF0000u);
                }
#pragma unroll
                for (int k = 0; k < 4; k++) {
                    unsigned int w = (&v1.x)[k];
                    acc[8 + 2 * k]     += wj * __uint_as_float(w << 16);
                    acc[8 + 2 * k + 1] += wj * __uint_as_float(w & 0xFFFF0000u);
                }
            }
        }
    }
#pragma unroll
    for (int k = 0; k < 16; k++) {
        acc[k] += __shfl_xor(acc[k], 8);
        acc[k] += __shfl_xor(acc[k], 16);
        acc[k] += __shfl_xor(acc[k], 32);
    }
#pragma unroll
    for (int m = 32; m >= 1; m >>= 1) sum += __shfl_xor(sum, m);
    float inv = (sum > 0.f) ? 1.f / sum : 1.f;

    float a0 = acc[g * 2] * inv;
    float a1 = acc[g * 2 + 1] * inv;
    float2 o;
    o.x = (a0 > 0.f) ? a0 : expm1f(a0);
    o.y = (a1 > 0.f) ? a1 : expm1f(a1);
    *(float2*)outp = o;
}

// ---------------- launcher ----------------
extern "C" void kernel_launch(void* const* d_in, const int* in_sizes, int n_in,
                              void* d_out, int out_size, void* d_ws, size_t ws_size,
                              hipStream_t stream) {
    const float* h      = (const float*)d_in[0];
    const int*   src    = (const int*)d_in[1];
    const int*   dst    = (const int*)d_in[2];
    const float* W_fc   = (const float*)d_in[3];
    const float* attn_w = (const float*)d_in[4];
    float* out = (float*)d_out;

    char* ws = (char*)d_ws;
    unsigned short* zb = (unsigned short*)(ws + OFF_ZB);
    float* s1       = (float*)(ws + OFF_S1);
    float* s2       = (float*)(ws + OFF_S2);
    int*   deg8     = (int*)(ws + OFF_DEG8);
    int*   offs     = (int*)(ws + OFF_OFFS);
    int*   offs2    = (int*)(ws + OFF_OFFS2);
    int*   blocksum = (int*)(ws + OFF_BSUM);
    unsigned short* rank = (unsigned short*)(ws + OFF_RANK);
    unsigned short* srcs = (unsigned short*)(ws + OFF_SRCS);
    unsigned short* WT   = (unsigned short*)(ws + OFF_WT);
    unsigned short* pre8 = (unsigned short*)(ws + OFF_PRE8);

    hipMemsetAsync(deg8, 0, 8 * N_NODES * sizeof(int), stream);

    deg_wt<<<DEG_NB + WT_NB, 256, 0, stream>>>(W_fc, dst, deg8, rank, WT);
    gemm_scan<<<GEMM_NB + SCAN_NB, 512, 0, stream>>>(h, WT, attn_w, zb, s1, s2,
                                                     deg8, offs, blocksum, pre8);
    scatter_k<<<DEG_NB, 256, 0, stream>>>(src, dst, rank, offs, blocksum, pre8, srcs, offs2);
    aggregate<<<(N_NODES * 64) / 256, 256, 0, stream>>>(zb, offs2, srcs, s1, s2, out);
}

// Round 11
// 104.856 us; speedup vs baseline: 1.1990x; 1.0639x over previous
//
#include <hip/hip_runtime.h>
#include <math.h>

#define N_NODES 50000
#define N_EDGES 800000
#define IN_DIM 256
#define OUT_DIM 128
#define ALPHA 0.2f

#define ZERO_NB 391          // zero deg8: 391*256*4 ints >= 400000
#define WT_NB   16
#define GEMM_NB 391          // ceil(50000/128), 8 waves, 16 rows/wave
#define DEG_NB  1563         // ceil(800000/512)
#define SCAN_NB 196          // (N_NODES+255)/256

typedef __attribute__((ext_vector_type(8))) short short8;
typedef __attribute__((ext_vector_type(4))) float f32x4;
typedef __attribute__((ext_vector_type(2))) float f32x2;

// ---------------- workspace layout (bytes) ----------------
#define OFF_ZB    0u          // z bf16: 12,800,000
#define OFF_S1    12800000u
#define OFF_S2    13000000u
#define OFF_DEG8  13200000u   // 8 * 50000 * 4 (XCD-partitioned counters)
#define OFF_OFFS  14800000u
#define OFF_OFFS2 15000000u   // 50001 ints
#define OFF_BSUM  15200064u
#define OFF_RANK  15201088u   // u16
#define OFF_SRCS  16801088u   // u16
#define OFF_WT    18401088u   // 65,536
#define OFF_PRE8  18466624u   // u16: 50000*8*2
// total ~19.3 MB

static __device__ __forceinline__ unsigned short f2bf_rne(float f) {
    unsigned int u = __float_as_uint(f);
    unsigned int r = (u + 0x7FFFu + ((u >> 16) & 1u)) >> 16;
    return (unsigned short)r;
}
static __device__ __forceinline__ unsigned int pack2bf(float lo, float hi) {
    return (unsigned int)f2bf_rne(lo) | ((unsigned int)f2bf_rne(hi) << 16);
}

// ---------------- init: zero deg8 | WT transpose ----------------
__global__ __launch_bounds__(256) void init_wt(const float* __restrict__ W,
                                               int* __restrict__ deg8,
                                               unsigned short* __restrict__ WT) {
    int b = blockIdx.x, t = threadIdx.x;
    if (b < ZERO_NB) {
        int i = (b * 256 + t) * 4;
        if (i < 8 * N_NODES)
            *(int4*)(deg8 + i) = make_int4(0, 0, 0, 0);
    } else {
        int idx = ((b - ZERO_NB) * 256 + t) * 8;   // WT[c][k] = bf16(W[k][c])
        int c = idx >> 8, k0 = idx & 255;
        unsigned int uu[4];
#pragma unroll
        for (int q = 0; q < 4; q++) {
            float lo = W[(size_t)(k0 + 2 * q) * OUT_DIM + c];
            float hi = W[(size_t)(k0 + 2 * q + 1) * OUT_DIM + c];
            uu[q] = pack2bf(lo, hi);
        }
        *(uint4*)(WT + idx) = make_uint4(uu[0], uu[1], uu[2], uu[3]);
    }
}

// ---------------- fused: GEMM (LDS-resident B, barrier-free K-loop) | deg+rank ----------------
// GEMM blocks [0,GEMM_NB): 512 thr = 8 waves, tile 128x128, K=256, s1/s2 epilogue.
// deg blocks [GEMM_NB, +DEG_NB): XCD-partitioned atomics, x = (b-GEMM_NB)&7.
__global__ __launch_bounds__(512) void gemm_deg(const float* __restrict__ h,
                                                const unsigned short* __restrict__ WT,
                                                const float* __restrict__ attn,
                                                unsigned short* __restrict__ zb,
                                                float* __restrict__ s1,
                                                float* __restrict__ s2,
                                                const int* __restrict__ dst,
                                                int* __restrict__ deg8,
                                                unsigned short* __restrict__ rank) {
    __shared__ char smem[65536];
    const int t = threadIdx.x;

    if (blockIdx.x >= GEMM_NB) {       // ---- deg_rank path ----
        int bb = blockIdx.x - GEMM_NB;
        int e = bb * 512 + t;
        int x = bb & 7;
        if (e < N_EDGES)
            rank[e] = (unsigned short)atomicAdd(&deg8[x * N_NODES + dst[e]], 1);
        return;
    }

    // ---- GEMM path ----
    const int lane = t & 63, w = t >> 6;
    const int row0 = blockIdx.x * 128;
    const int m16 = lane & 15, kb = lane >> 4;

    // stage B once: linear global read, swizzled LDS write
#pragma unroll
    for (int j = 0; j < 8; j++) {
        int jj = w * 8 + j;
        int cc = jj * 2 + (lane >> 5);      // col 0..127
        int gs = lane & 31;                 // 16B granule 0..31
        const uint4 v = *(const uint4*)(WT + (size_t)cc * IN_DIM + gs * 8);
        *(uint4*)(smem + cc * 512 + ((gs ^ (cc & 7)) * 16)) = v;
    }
    __syncthreads();

    const int rA = row0 + w * 16 + m16;
    const float* hrow = h + (size_t)min(rA, N_NODES - 1) * IN_DIM + kb * 8;

    f32x4 acc[8];
#pragma unroll
    for (int ct = 0; ct < 8; ct++) acc[ct] = (f32x4){0.f, 0.f, 0.f, 0.f};

    float4 v0 = *(const float4*)(hrow);
    float4 v1 = *(const float4*)(hrow + 4);
#pragma unroll
    for (int kc = 0; kc < 8; kc++) {
        const float4 c0 = v0, c1 = v1;
        if (kc < 7) {
            v0 = *(const float4*)(hrow + (kc + 1) * 32);
            v1 = *(const float4*)(hrow + (kc + 1) * 32 + 4);
        }
        short8 af;
        af[0] = (short)f2bf_rne(c0.x); af[1] = (short)f2bf_rne(c0.y);
        af[2] = (short)f2bf_rne(c0.z); af[3] = (short)f2bf_rne(c0.w);
        af[4] = (short)f2bf_rne(c1.x); af[5] = (short)f2bf_rne(c1.y);
        af[6] = (short)f2bf_rne(c1.z); af[7] = (short)f2bf_rne(c1.w);
        const char* bbase = smem + m16 * 512 + (((kc * 4 + kb) ^ (m16 & 7)) * 16);
#pragma unroll
        for (int ct = 0; ct < 8; ct++) {
            const short8 bf = *(const short8*)(bbase + ct * 8192);
            acc[ct] = __builtin_amdgcn_mfma_f32_16x16x32_bf16(af, bf, acc[ct], 0, 0, 0);
        }
    }

    // ---- epilogue: s1/s2 from f32 acc, zb bf16 store ----
    float a1v[8], a2v[8];
#pragma unroll
    for (int ct = 0; ct < 8; ct++) {
        a1v[ct] = attn[ct * 16 + m16];
        a2v[ct] = attn[OUT_DIM + ct * 16 + m16];
    }
#pragma unroll
    for (int i = 0; i < 4; i++) {
        int rr = row0 + w * 16 + kb * 4 + i;
        float q1 = 0.f, q2 = 0.f;
#pragma unroll
        for (int ct = 0; ct < 8; ct++) {
            q1 += acc[ct][i] * a1v[ct];
            q2 += acc[ct][i] * a2v[ct];
        }
        q1 += __shfl_xor(q1, 1); q1 += __shfl_xor(q1, 2);
        q1 += __shfl_xor(q1, 4); q1 += __shfl_xor(q1, 8);
        q2 += __shfl_xor(q2, 1); q2 += __shfl_xor(q2, 2);
        q2 += __shfl_xor(q2, 4); q2 += __shfl_xor(q2, 8);
        if (m16 == 0 && rr < N_NODES) { s1[rr] = q1; s2[rr] = q2; }
        if (rr < N_NODES) {
#pragma unroll
            for (int ct = 0; ct < 8; ct++)
                zb[(size_t)rr * OUT_DIM + ct * 16 + m16] = f2bf_rne(acc[ct][i]);
        }
    }
}

// ---------------- scan: sum 8 partitions, emit pre8, chunk-scan totals ----------------
__global__ __launch_bounds__(256) void scan1(const int* __restrict__ deg8,
                                             int* __restrict__ offs,
                                             int* __restrict__ blocksum,
                                             unsigned short* __restrict__ pre8) {
    __shared__ int s[256];
    int t = threadIdx.x;
    int i = blockIdx.x * 256 + t;
    int tot = 0;
    if (i < N_NODES) {
        unsigned short pre[8];
#pragma unroll
        for (int x = 0; x < 8; x++) {
            pre[x] = (unsigned short)tot;
            tot += deg8[x * N_NODES + i];
        }
        ushort4 p0, p1;
        p0.x = pre[0]; p0.y = pre[1]; p0.z = pre[2]; p0.w = pre[3];
        p1.x = pre[4]; p1.y = pre[5]; p1.z = pre[6]; p1.w = pre[7];
        *(ushort4*)(pre8 + (size_t)i * 8) = p0;
        *(ushort4*)(pre8 + (size_t)i * 8 + 4) = p1;
    }
    s[t] = tot;
    __syncthreads();
    int v = tot;
    for (int ofs = 1; ofs < 256; ofs <<= 1) {
        int add = (t >= ofs) ? s[t - ofs] : 0;
        __syncthreads();
        v += add;
        s[t] = v;
        __syncthreads();
    }
    if (i < N_NODES) offs[i] = v - tot;
    if (t == 255) blocksum[blockIdx.x] = v;
}

// ---------------- scatter (in-LDS scan of blocksums; emits folded offs2) ----------------
__global__ __launch_bounds__(256) void scatter_k(const int* __restrict__ src, const int* __restrict__ dst,
                                                 const unsigned short* __restrict__ rank,
                                                 const int* __restrict__ offs,
                                                 const int* __restrict__ blocksum,
                                                 const unsigned short* __restrict__ pre8,
                                                 unsigned short* __restrict__ srcs,
                                                 int* __restrict__ offs2) {
    __shared__ int sbo[256];
    int t = threadIdx.x;
    int d0 = (t < SCAN_NB) ? blocksum[t] : 0;
    sbo[t] = d0;
    __syncthreads();
    int v = d0;
    for (int ofs = 1; ofs < 256; ofs <<= 1) {
        int add = (t >= ofs) ? sbo[t - ofs] : 0;
        __syncthreads();
        v += add;
        sbo[t] = v;
        __syncthreads();
    }
    int excl = (t > 0) ? sbo[t - 1] : 0;
    __syncthreads();
    sbo[t] = excl;
    __syncthreads();

    if (blockIdx.x < SCAN_NB) {
        int i = blockIdx.x * 256 + t;
        if (i < N_NODES) offs2[i] = offs[i] + sbo[blockIdx.x];
        if (blockIdx.x == 0 && t == 0) offs2[N_NODES] = N_EDGES;
    }

    int e = blockIdx.x * 256 + t;
    if (e < N_EDGES) {
        int d = dst[e];
        int x = (e >> 9) & 7;               // deg block = e/512, partition = block&7
        int pos = offs[d] + sbo[d >> 8] + (int)pre8[(size_t)d * 8 + x] + (int)rank[e];
        srcs[pos] = (unsigned short)src[e];
    }
}

// ---------------- per-dst softmax + weighted gather-sum (f32x2-packed unpack) ----------------
__global__ __launch_bounds__(256) void aggregate(const unsigned short* __restrict__ zb,
                                                 const int* __restrict__ offs2,
                                                 const unsigned short* __restrict__ srcs,
                                                 const float* __restrict__ s1,
                                                 const float* __restrict__ s2,
                                                 float* __restrict__ out) {
    int wid = (blockIdx.x * blockDim.x + threadIdx.x) >> 6;
    int lane = threadIdx.x & 63;
    if (wid >= N_NODES) return;
    const int g = lane >> 3;
    const int l = lane & 7;
    float* outp = out + (size_t)wid * OUT_DIM + l * 16 + g * 2;

    int base = offs2[wid];
    int len = offs2[wid + 1] - base;
    if (len == 0) {
        *(float2*)outp = make_float2(0.f, 0.f);
        return;
    }
    const float s2v = s2[wid];

    float sum = 0.f;
    f32x2 acc2[8];
#pragma unroll
    for (int k = 0; k < 8; k++) acc2[k] = (f32x2){0.f, 0.f};

    for (int c0 = 0; c0 < len; c0 += 64) {
        int i = c0 + lane;
        float ex = 0.f;
        int sj = 0;
        if (i < len) {
            sj = srcs[base + i];
            float lg = s1[sj] + s2v;
            lg = (lg >= 0.f) ? lg : ALPHA * lg;
            ex = __expf(lg);
        }
        sum += ex;
        int cnt = min(64, len - c0);
        for (int j0 = 0; j0 < cnt; j0 += 8) {
            int j = j0 + g;
            float wj = __shfl(ex, j);
            int s = __shfl(sj, j);
            if (j < cnt) {
                const uint4* rp = (const uint4*)(zb + (size_t)s * OUT_DIM);
                const uint4 v0 = rp[l * 2];
                const uint4 v1 = rp[l * 2 + 1];
#pragma unroll
                for (int k = 0; k < 4; k++) {
                    unsigned int w = (&v0.x)[k];
                    f32x2 f;
                    f.x = __uint_as_float(w << 16);
                    f.y = __uint_as_float(w & 0xFFFF0000u);
                    acc2[k] += wj * f;      // v_pk_fma_f32 target
                }
#pragma unroll
                for (int k = 0; k < 4; k++) {
                    unsigned int w = (&v1.x)[k];
                    f32x2 f;
                    f.x = __uint_as_float(w << 16);
                    f.y = __uint_as_float(w & 0xFFFF0000u);
                    acc2[4 + k] += wj * f;
                }
            }
        }
    }
#pragma unroll
    for (int k = 0; k < 8; k++) {
        acc2[k].x += __shfl_xor(acc2[k].x, 8);
        acc2[k].y += __shfl_xor(acc2[k].y, 8);
        acc2[k].x += __shfl_xor(acc2[k].x, 16);
        acc2[k].y += __shfl_xor(acc2[k].y, 16);
        acc2[k].x += __shfl_xor(acc2[k].x, 32);
        acc2[k].y += __shfl_xor(acc2[k].y, 32);
    }
#pragma unroll
    for (int m = 32; m >= 1; m >>= 1) sum += __shfl_xor(sum, m);
    float inv = (sum > 0.f) ? 1.f / sum : 1.f;

    // lane (g,l) stores features l*16 + g*2 .. +1  -> acc2[g]
    float a0 = acc2[g].x * inv;
    float a1 = acc2[g].y * inv;
    float2 o;
    o.x = (a0 > 0.f) ? a0 : expm1f(a0);
    o.y = (a1 > 0.f) ? a1 : expm1f(a1);
    *(float2*)outp = o;
}

// ---------------- launcher ----------------
extern "C" void kernel_launch(void* const* d_in, const int* in_sizes, int n_in,
                              void* d_out, int out_size, void* d_ws, size_t ws_size,
                              hipStream_t stream) {
    const float* h      = (const float*)d_in[0];
    const int*   src    = (const int*)d_in[1];
    const int*   dst    = (const int*)d_in[2];
    const float* W_fc   = (const float*)d_in[3];
    const float* attn_w = (const float*)d_in[4];
    float* out = (float*)d_out;

    char* ws = (char*)d_ws;
    unsigned short* zb = (unsigned short*)(ws + OFF_ZB);
    float* s1       = (float*)(ws + OFF_S1);
    float* s2       = (float*)(ws + OFF_S2);
    int*   deg8     = (int*)(ws + OFF_DEG8);
    int*   offs     = (int*)(ws + OFF_OFFS);
    int*   offs2    = (int*)(ws + OFF_OFFS2);
    int*   blocksum = (int*)(ws + OFF_BSUM);
    unsigned short* rank = (unsigned short*)(ws + OFF_RANK);
    unsigned short* srcs = (unsigned short*)(ws + OFF_SRCS);
    unsigned short* WT   = (unsigned short*)(ws + OFF_WT);
    unsigned short* pre8 = (unsigned short*)(ws + OFF_PRE8);

    init_wt<<<ZERO_NB + WT_NB, 256, 0, stream>>>(W_fc, deg8, WT);
    gemm_deg<<<GEMM_NB + DEG_NB, 512, 0, stream>>>(h, WT, attn_w, zb, s1, s2,
                                                   dst, deg8, rank);
    scan1<<<SCAN_NB, 256, 0, stream>>>(deg8, offs, blocksum, pre8);
    scatter_k<<<(N_EDGES + 255) / 256, 256, 0, stream>>>(src, dst, rank, offs, blocksum,
                                                         pre8, srcs, offs2);
    aggregate<<<(N_NODES * 64) / 256, 256, 0, stream>>>(zb, offs2, srcs, s1, s2, out);
}

// Round 12
// 103.144 us; speedup vs baseline: 1.2189x; 1.0166x over previous
//
#include <hip/hip_runtime.h>
#include <math.h>

#define N_NODES 50000
#define N_EDGES 800000
#define IN_DIM 256
#define OUT_DIM 128
#define ALPHA 0.2f

#define ZERO_NB 391          // zero deg8: 391*256*4 ints >= 400000
#define WT_NB   16
#define GEMM_NB 391          // ceil(50000/128), 8 waves, 16 rows/wave
#define DEG_NB  1563         // ceil(800000/512)
#define SCAN_NB 196          // (N_NODES+255)/256

typedef __attribute__((ext_vector_type(8))) short short8;
typedef __attribute__((ext_vector_type(4))) float f32x4;
typedef __attribute__((ext_vector_type(2))) float f32x2;

// ---------------- workspace layout (bytes) ----------------
#define OFF_ZB    0u          // z bf16: 12,800,000
#define OFF_S1    12800000u
#define OFF_S2    13000000u
#define OFF_DEG8  13200000u   // 8 * 50000 * 4 (XCD-partitioned counters)
#define OFF_OFFS  14800000u
#define OFF_OFFS2 15000000u   // 50001 ints
#define OFF_BSUM  15200064u
#define OFF_RANK  15201088u   // u16
#define OFF_SRCS  16801088u   // u16
#define OFF_WT    18401088u   // 65,536
#define OFF_PRE8  18466624u   // u16: 50000*8*2
// total ~19.3 MB

static __device__ __forceinline__ unsigned short f2bf_rne(float f) {
    unsigned int u = __float_as_uint(f);
    unsigned int r = (u + 0x7FFFu + ((u >> 16) & 1u)) >> 16;
    return (unsigned short)r;
}
static __device__ __forceinline__ unsigned int pack2bf(float lo, float hi) {
    return (unsigned int)f2bf_rne(lo) | ((unsigned int)f2bf_rne(hi) << 16);
}

// ---------------- init: zero deg8 | WT transpose ----------------
__global__ __launch_bounds__(256) void init_wt(const float* __restrict__ W,
                                               int* __restrict__ deg8,
                                               unsigned short* __restrict__ WT) {
    int b = blockIdx.x, t = threadIdx.x;
    if (b < ZERO_NB) {
        int i = (b * 256 + t) * 4;
        if (i < 8 * N_NODES)
            *(int4*)(deg8 + i) = make_int4(0, 0, 0, 0);
    } else {
        int idx = ((b - ZERO_NB) * 256 + t) * 8;   // WT[c][k] = bf16(W[k][c])
        int c = idx >> 8, k0 = idx & 255;
        unsigned int uu[4];
#pragma unroll
        for (int q = 0; q < 4; q++) {
            float lo = W[(size_t)(k0 + 2 * q) * OUT_DIM + c];
            float hi = W[(size_t)(k0 + 2 * q + 1) * OUT_DIM + c];
            uu[q] = pack2bf(lo, hi);
        }
        *(uint4*)(WT + idx) = make_uint4(uu[0], uu[1], uu[2], uu[3]);
    }
}

// ---------------- fused: GEMM (32KB LDS, two-phase B) | deg+rank ----------------
// R11 lesson: 64KB static LDS was charged to the deg blocks too -> 2 blocks/CU,
// atomic latency unhidden. Two-phase B staging halves LDS -> 4 blocks/CU.
__global__ __launch_bounds__(512) void gemm_deg(const float* __restrict__ h,
                                                const unsigned short* __restrict__ WT,
                                                const float* __restrict__ attn,
                                                unsigned short* __restrict__ zb,
                                                float* __restrict__ s1,
                                                float* __restrict__ s2,
                                                const int* __restrict__ dst,
                                                int* __restrict__ deg8,
                                                unsigned short* __restrict__ rank) {
    __shared__ char smem[32768];
    const int t = threadIdx.x;

    if (blockIdx.x >= GEMM_NB) {       // ---- deg_rank path (no LDS use) ----
        int bb = blockIdx.x - GEMM_NB;
        int e = bb * 512 + t;
        int x = bb & 7;
        if (e < N_EDGES)
            rank[e] = (unsigned short)atomicAdd(&deg8[x * N_NODES + dst[e]], 1);
        return;
    }

    // ---- GEMM path: tile 128x128, K=256 in two 32KB halves ----
    const int lane = t & 63, w = t >> 6;
    const int row0 = blockIdx.x * 128;
    const int m16 = lane & 15, kb = lane >> 4;

    const int rA = row0 + w * 16 + m16;
    const float* hrow = h + (size_t)min(rA, N_NODES - 1) * IN_DIM + kb * 8;

    f32x4 acc[8];
#pragma unroll
    for (int ct = 0; ct < 8; ct++) acc[ct] = (f32x4){0.f, 0.f, 0.f, 0.f};

    float4 v0 = *(const float4*)(hrow);
    float4 v1 = *(const float4*)(hrow + 4);

#pragma unroll
    for (int half = 0; half < 2; half++) {
        if (half) __syncthreads();     // protect overwrite of half-0 data
        // stage this K-half: col cc granule gs (16B = 8 shorts of k)
#pragma unroll
        for (int q = 0; q < 4; q++) {
            int G = t * 4 + q;                  // 0..2047
            int cc = G >> 4, gs = G & 15;       // col 0..127, granule 0..15
            const uint4 v = *(const uint4*)(WT + (size_t)cc * IN_DIM + half * 128 + gs * 8);
            *(uint4*)(smem + cc * 256 + ((gs ^ (cc & 7)) * 16)) = v;
        }
        __syncthreads();
#pragma unroll
        for (int kcl = 0; kcl < 4; kcl++) {
            const float4 c0 = v0, c1 = v1;
            int nk = half * 4 + kcl + 1;
            if (nk < 8) {
                v0 = *(const float4*)(hrow + nk * 32);
                v1 = *(const float4*)(hrow + nk * 32 + 4);
            }
            short8 af;
            af[0] = (short)f2bf_rne(c0.x); af[1] = (short)f2bf_rne(c0.y);
            af[2] = (short)f2bf_rne(c0.z); af[3] = (short)f2bf_rne(c0.w);
            af[4] = (short)f2bf_rne(c1.x); af[5] = (short)f2bf_rne(c1.y);
            af[6] = (short)f2bf_rne(c1.z); af[7] = (short)f2bf_rne(c1.w);
            const char* bbase = smem + m16 * 256 + (((kcl * 4 + kb) ^ (m16 & 7)) * 16);
#pragma unroll
            for (int ct = 0; ct < 8; ct++) {
                const short8 bf = *(const short8*)(bbase + ct * 4096);
                acc[ct] = __builtin_amdgcn_mfma_f32_16x16x32_bf16(af, bf, acc[ct], 0, 0, 0);
            }
        }
    }

    // ---- epilogue: s1/s2 from f32 acc, zb bf16 store ----
    float a1v[8], a2v[8];
#pragma unroll
    for (int ct = 0; ct < 8; ct++) {
        a1v[ct] = attn[ct * 16 + m16];
        a2v[ct] = attn[OUT_DIM + ct * 16 + m16];
    }
#pragma unroll
    for (int i = 0; i < 4; i++) {
        int rr = row0 + w * 16 + kb * 4 + i;
        float q1 = 0.f, q2 = 0.f;
#pragma unroll
        for (int ct = 0; ct < 8; ct++) {
            q1 += acc[ct][i] * a1v[ct];
            q2 += acc[ct][i] * a2v[ct];
        }
        q1 += __shfl_xor(q1, 1); q1 += __shfl_xor(q1, 2);
        q1 += __shfl_xor(q1, 4); q1 += __shfl_xor(q1, 8);
        q2 += __shfl_xor(q2, 1); q2 += __shfl_xor(q2, 2);
        q2 += __shfl_xor(q2, 4); q2 += __shfl_xor(q2, 8);
        if (m16 == 0 && rr < N_NODES) { s1[rr] = q1; s2[rr] = q2; }
        if (rr < N_NODES) {
#pragma unroll
            for (int ct = 0; ct < 8; ct++)
                zb[(size_t)rr * OUT_DIM + ct * 16 + m16] = f2bf_rne(acc[ct][i]);
        }
    }
}

// ---------------- scan: sum 8 partitions, emit pre8, chunk-scan totals ----------------
__global__ __launch_bounds__(256) void scan1(const int* __restrict__ deg8,
                                             int* __restrict__ offs,
                                             int* __restrict__ blocksum,
                                             unsigned short* __restrict__ pre8) {
    __shared__ int s[256];
    int t = threadIdx.x;
    int i = blockIdx.x * 256 + t;
    int tot = 0;
    if (i < N_NODES) {
        unsigned short pre[8];
#pragma unroll
        for (int x = 0; x < 8; x++) {
            pre[x] = (unsigned short)tot;
            tot += deg8[x * N_NODES + i];
        }
        ushort4 p0, p1;
        p0.x = pre[0]; p0.y = pre[1]; p0.z = pre[2]; p0.w = pre[3];
        p1.x = pre[4]; p1.y = pre[5]; p1.z = pre[6]; p1.w = pre[7];
        *(ushort4*)(pre8 + (size_t)i * 8) = p0;
        *(ushort4*)(pre8 + (size_t)i * 8 + 4) = p1;
    }
    s[t] = tot;
    __syncthreads();
    int v = tot;
    for (int ofs = 1; ofs < 256; ofs <<= 1) {
        int add = (t >= ofs) ? s[t - ofs] : 0;
        __syncthreads();
        v += add;
        s[t] = v;
        __syncthreads();
    }
    if (i < N_NODES) offs[i] = v - tot;
    if (t == 255) blocksum[blockIdx.x] = v;
}

// ---------------- scatter (in-LDS scan of blocksums; emits folded offs2) ----------------
__global__ __launch_bounds__(256) void scatter_k(const int* __restrict__ src, const int* __restrict__ dst,
                                                 const unsigned short* __restrict__ rank,
                                                 const int* __restrict__ offs,
                                                 const int* __restrict__ blocksum,
                                                 const unsigned short* __restrict__ pre8,
                                                 unsigned short* __restrict__ srcs,
                                                 int* __restrict__ offs2) {
    __shared__ int sbo[256];
    int t = threadIdx.x;
    int d0 = (t < SCAN_NB) ? blocksum[t] : 0;
    sbo[t] = d0;
    __syncthreads();
    int v = d0;
    for (int ofs = 1; ofs < 256; ofs <<= 1) {
        int add = (t >= ofs) ? sbo[t - ofs] : 0;
        __syncthreads();
        v += add;
        sbo[t] = v;
        __syncthreads();
    }
    int excl = (t > 0) ? sbo[t - 1] : 0;
    __syncthreads();
    sbo[t] = excl;
    __syncthreads();

    if (blockIdx.x < SCAN_NB) {
        int i = blockIdx.x * 256 + t;
        if (i < N_NODES) offs2[i] = offs[i] + sbo[blockIdx.x];
        if (blockIdx.x == 0 && t == 0) offs2[N_NODES] = N_EDGES;
    }

    int e = blockIdx.x * 256 + t;
    if (e < N_EDGES) {
        int d = dst[e];
        int x = (e >> 9) & 7;               // deg block = e/512, partition = block&7
        int pos = offs[d] + sbo[d >> 8] + (int)pre8[(size_t)d * 8 + x] + (int)rank[e];
        srcs[pos] = (unsigned short)src[e];
    }
}

// ---------------- per-dst softmax + weighted gather-sum (2 edges/group in flight) ----------------
__global__ __launch_bounds__(256) void aggregate(const unsigned short* __restrict__ zb,
                                                 const int* __restrict__ offs2,
                                                 const unsigned short* __restrict__ srcs,
                                                 const float* __restrict__ s1,
                                                 const float* __restrict__ s2,
                                                 float* __restrict__ out) {
    int wid = (blockIdx.x * blockDim.x + threadIdx.x) >> 6;
    int lane = threadIdx.x & 63;
    if (wid >= N_NODES) return;
    const int g = lane >> 3;
    const int l = lane & 7;
    float* outp = out + (size_t)wid * OUT_DIM + l * 16 + g * 2;

    int base = offs2[wid];
    int len = offs2[wid + 1] - base;
    if (len == 0) {
        *(float2*)outp = make_float2(0.f, 0.f);
        return;
    }
    const float s2v = s2[wid];

    float sum = 0.f;
    f32x2 acc2[8];
#pragma unroll
    for (int k = 0; k < 8; k++) acc2[k] = (f32x2){0.f, 0.f};

    for (int c0 = 0; c0 < len; c0 += 64) {
        int i = c0 + lane;
        float ex = 0.f;
        int sj = 0;
        if (i < len) {
            sj = srcs[base + i];
            float lg = s1[sj] + s2v;
            lg = (lg >= 0.f) ? lg : ALPHA * lg;
            ex = __expf(lg);
        }
        sum += ex;
        int cnt = min(64, len - c0);
        int j0 = 0;
        // main: two edges per group in flight (branch-free, 4 loads outstanding)
        for (; j0 + 16 <= cnt; j0 += 16) {
            int ja = j0 + g, jb = j0 + 8 + g;
            float wa = __shfl(ex, ja), wb = __shfl(ex, jb);
            int sa = __shfl(sj, ja), sb = __shfl(sj, jb);
            const uint4* rpa = (const uint4*)(zb + (size_t)sa * OUT_DIM);
            const uint4* rpb = (const uint4*)(zb + (size_t)sb * OUT_DIM);
            const uint4 a0 = rpa[l * 2];
            const uint4 a1 = rpa[l * 2 + 1];
            const uint4 b0 = rpb[l * 2];
            const uint4 b1 = rpb[l * 2 + 1];
#pragma unroll
            for (int k = 0; k < 4; k++) {
                unsigned int u = (&a0.x)[k];
                f32x2 f;
                f.x = __uint_as_float(u << 16);
                f.y = __uint_as_float(u & 0xFFFF0000u);
                acc2[k] += wa * f;
                u = (&b0.x)[k];
                f.x = __uint_as_float(u << 16);
                f.y = __uint_as_float(u & 0xFFFF0000u);
                acc2[k] += wb * f;
            }
#pragma unroll
            for (int k = 0; k < 4; k++) {
                unsigned int u = (&a1.x)[k];
                f32x2 f;
                f.x = __uint_as_float(u << 16);
                f.y = __uint_as_float(u & 0xFFFF0000u);
                acc2[4 + k] += wa * f;
                u = (&b1.x)[k];
                f.x = __uint_as_float(u << 16);
                f.y = __uint_as_float(u & 0xFFFF0000u);
                acc2[4 + k] += wb * f;
            }
        }
        // tail
        for (; j0 < cnt; j0 += 8) {
            int j = j0 + g;
            float wj = __shfl(ex, j);
            int s = __shfl(sj, j);
            if (j < cnt) {
                const uint4* rp = (const uint4*)(zb + (size_t)s * OUT_DIM);
                const uint4 v0 = rp[l * 2];
                const uint4 v1 = rp[l * 2 + 1];
#pragma unroll
                for (int k = 0; k < 4; k++) {
                    unsigned int u = (&v0.x)[k];
                    f32x2 f;
                    f.x = __uint_as_float(u << 16);
                    f.y = __uint_as_float(u & 0xFFFF0000u);
                    acc2[k] += wj * f;
                }
#pragma unroll
                for (int k = 0; k < 4; k++) {
                    unsigned int u = (&v1.x)[k];
                    f32x2 f;
                    f.x = __uint_as_float(u << 16);
                    f.y = __uint_as_float(u & 0xFFFF0000u);
                    acc2[4 + k] += wj * f;
                }
            }
        }
    }
#pragma unroll
    for (int k = 0; k < 8; k++) {
        acc2[k].x += __shfl_xor(acc2[k].x, 8);
        acc2[k].y += __shfl_xor(acc2[k].y, 8);
        acc2[k].x += __shfl_xor(acc2[k].x, 16);
        acc2[k].y += __shfl_xor(acc2[k].y, 16);
        acc2[k].x += __shfl_xor(acc2[k].x, 32);
        acc2[k].y += __shfl_xor(acc2[k].y, 32);
    }
#pragma unroll
    for (int m = 32; m >= 1; m >>= 1) sum += __shfl_xor(sum, m);
    float inv = (sum > 0.f) ? 1.f / sum : 1.f;

    float a0 = acc2[g].x * inv;
    float a1 = acc2[g].y * inv;
    float2 o;
    o.x = (a0 > 0.f) ? a0 : expm1f(a0);
    o.y = (a1 > 0.f) ? a1 : expm1f(a1);
    *(float2*)outp = o;
}

// ---------------- launcher ----------------
extern "C" void kernel_launch(void* const* d_in, const int* in_sizes, int n_in,
                              void* d_out, int out_size, void* d_ws, size_t ws_size,
                              hipStream_t stream) {
    const float* h      = (const float*)d_in[0];
    const int*   src    = (const int*)d_in[1];
    const int*   dst    = (const int*)d_in[2];
    const float* W_fc   = (const float*)d_in[3];
    const float* attn_w = (const float*)d_in[4];
    float* out = (float*)d_out;

    char* ws = (char*)d_ws;
    unsigned short* zb = (unsigned short*)(ws + OFF_ZB);
    float* s1       = (float*)(ws + OFF_S1);
    float* s2       = (float*)(ws + OFF_S2);
    int*   deg8     = (int*)(ws + OFF_DEG8);
    int*   offs     = (int*)(ws + OFF_OFFS);
    int*   offs2    = (int*)(ws + OFF_OFFS2);
    int*   blocksum = (int*)(ws + OFF_BSUM);
    unsigned short* rank = (unsigned short*)(ws + OFF_RANK);
    unsigned short* srcs = (unsigned short*)(ws + OFF_SRCS);
    unsigned short* WT   = (unsigned short*)(ws + OFF_WT);
    unsigned short* pre8 = (unsigned short*)(ws + OFF_PRE8);

    init_wt<<<ZERO_NB + WT_NB, 256, 0, stream>>>(W_fc, deg8, WT);
    gemm_deg<<<GEMM_NB + DEG_NB, 512, 0, stream>>>(h, WT, attn_w, zb, s1, s2,
                                                   dst, deg8, rank);
    scan1<<<SCAN_NB, 256, 0, stream>>>(deg8, offs, blocksum, pre8);
    scatter_k<<<(N_EDGES + 255) / 256, 256, 0, stream>>>(src, dst, rank, offs, blocksum,
                                                         pre8, srcs, offs2);
    aggregate<<<(N_NODES * 64) / 256, 256, 0, stream>>>(zb, offs2, srcs, s1, s2, out);
}